// Round 5
// baseline (586.017 us; speedup 1.0000x reference)
//
#include <hip/hip_runtime.h>
#include <stdint.h>

typedef int v4i  __attribute__((ext_vector_type(4)));
typedef int v16i __attribute__((ext_vector_type(16)));

// ---------------------------------------------------------------------------
// async global->LDS, 16 bytes per lane. LDS dest is wave-uniform base +
// lane*16 (HW takes readfirstlane of the provided pointer), so each thread
// passes its own &lds[t*16] and lane 0 of each wave carries the wave base.
// ---------------------------------------------------------------------------
__device__ __forceinline__ void async_load16(const void* g, void* l) {
    auto gp = (const __attribute__((address_space(1))) unsigned int*)(uintptr_t)g;
    auto lp = (__attribute__((address_space(3))) unsigned int*)(unsigned int)(uintptr_t)l;
    __builtin_amdgcn_global_load_lds(gp, lp, 16, 0, 0);
}

// ---------------------------------------------------------------------------
// ws scalar slots: [0..1] uint absmax bits (x, w); floats at byte 8:
// sc[0]=s_x, sc[1]=s_w, sc[2]=1/(s_x*s_w)
// ---------------------------------------------------------------------------
__global__ void k_init(unsigned* bits) {
    if (threadIdx.x < 2) bits[threadIdx.x] = 0u;
}

// Fused absmax over both tensors: blocks [0,XB) scan x, [XB,grid) scan w.
// Branch is block-uniform (no divergence); w-work hides under x-work.
__global__ void k_absmax2(const float4* __restrict__ x, int nx4,
                          const float4* __restrict__ w, int nw4,
                          unsigned* __restrict__ bits) {
    const int XB = 2048;
    const float4* in; int n4, b, nb; unsigned* ob;
    if (blockIdx.x < XB) { in = x; n4 = nx4; b = blockIdx.x;      nb = XB;              ob = bits;     }
    else                 { in = w; n4 = nw4; b = blockIdx.x - XB; nb = gridDim.x - XB;  ob = bits + 1; }
    float m = 0.0f;
    int stride = nb * blockDim.x;
    for (int i = b * blockDim.x + threadIdx.x; i < n4; i += stride) {
        float4 v = in[i];
        m = fmaxf(m, fmaxf(fmaxf(fabsf(v.x), fabsf(v.y)),
                           fmaxf(fabsf(v.z), fabsf(v.w))));
    }
    #pragma unroll
    for (int off = 32; off > 0; off >>= 1)
        m = fmaxf(m, __shfl_down(m, off, 64));
    __shared__ float red[4];
    int lane = threadIdx.x & 63, wv = threadIdx.x >> 6;
    if (lane == 0) red[wv] = m;
    __syncthreads();
    if (threadIdx.x == 0) {
        m = fmaxf(fmaxf(red[0], red[1]), fmaxf(red[2], red[3]));
        // |x| >= 0: IEEE bit pattern of non-negative floats is order-preserving
        atomicMax(ob, __float_as_uint(m));
    }
}

__global__ void k_scales(const unsigned* __restrict__ bits, float* __restrict__ sc) {
    float s[2];
    for (int i = 0; i < 2; ++i) {
        float m = __uint_as_float(bits[i]);
        int ex = 0;
        if (m > 0.0f) {
            int e;
            float f = frexpf(m, &e);      // m = f * 2^e, f in [0.5, 1)
            ex = (f == 0.5f) ? (e - 1) : e;  // exact ceil(log2(m))
        }
        s[i] = ldexpf(1.0f, 7 - ex);       // 2^(8 - ex - 1)
    }
    sc[0] = s[0];
    sc[1] = s[1];
    sc[2] = 1.0f / (s[0] * s[1]);          // powers of two: exact
}

// Fused quant of both tensors. round-half-even (rintf) == jnp.round;
// clip AFTER round, matching reference.
__global__ void k_quant2(const float4* __restrict__ x, int* __restrict__ qx, int nx4,
                         const float4* __restrict__ w, int* __restrict__ qw, int nw4,
                         const float* __restrict__ scp) {
    const int XB = 4096;
    const float4* in; int* out; int n4, b, nb; float s;
    if (blockIdx.x < XB) { in = x; out = qx; n4 = nx4; b = blockIdx.x;      nb = XB;             s = scp[0]; }
    else                 { in = w; out = qw; n4 = nw4; b = blockIdx.x - XB; nb = gridDim.x - XB; s = scp[1]; }
    int stride = nb * blockDim.x;
    for (int i = b * blockDim.x + threadIdx.x; i < n4; i += stride) {
        float4 v = in[i];
        int qa = (int)rintf(v.x * s); qa = qa > 127 ? 127 : (qa < -127 ? -127 : qa);
        int qb = (int)rintf(v.y * s); qb = qb > 127 ? 127 : (qb < -127 ? -127 : qb);
        int qc = (int)rintf(v.z * s); qc = qc > 127 ? 127 : (qc < -127 ? -127 : qc);
        int qd = (int)rintf(v.w * s); qd = qd > 127 ? 127 : (qd < -127 ? -127 : qd);
        out[i] = (qa & 0xff) | ((qb & 0xff) << 8) | ((qc & 0xff) << 16) | (qd << 24);
    }
}

// ---------------------------------------------------------------------------
// int8 NT GEMM: C[m][n] = sum_k A[m][k] * B[n][k], both K-major.
// 128x128 tile, BK=128 (rows = 128 B), 256 threads = 4 waves (2x2 of 64x64).
// BK=128 halves the K-step count (16->8) vs baseline: at a 2-barrier
// structure the critical path is stage+vmcnt+barrier (m233), so fewer,
// larger phases is the main lever. LDS tiles are XOR-swizzled (T2):
// physical chunk q of row p holds logical chunk q^(p&7); global_load_lds
// writes linearly, so the swizzle is applied by permuting the per-lane
// GLOBAL source chunk (involution), and the same XOR is applied on the
// ds_read_b128 address (rule #21: both sides). Post-swizzle: 4 hits/bank
// per 32-lane phase = b128 data-path floor (was 16).
// Fragment layouts (verified in the 602.5us harness run, unchanged):
//   A: lane holds A[m = lane&31][k = kc*32 + (lane>>5)*16 + j], j=0..15
//   B: lane holds B[n = lane&31][same k slice]
//   C/D: col = lane&31, row = (reg&3) + 8*(reg>>2) + 4*(lane>>5)
// ---------------------------------------------------------------------------
__global__ __launch_bounds__(256) void k_gemm(const signed char* __restrict__ A,
                                              const signed char* __restrict__ B,
                                              float* __restrict__ out,
                                              const float* __restrict__ scp) {
    __shared__ __align__(16) signed char As[128 * 128];
    __shared__ __align__(16) signed char Bs[128 * 128];
    const int tid  = threadIdx.x;
    const int lane = tid & 63;
    const int wave = tid >> 6;
    const int wm   = wave & 1;
    const int wn   = wave >> 1;
    const int l31  = lane & 31;
    const int lhi  = lane >> 5;

    // T1: XCD-bijective swizzle. nwg=4096 (%8==0). XCD j gets orig===j (mod 8),
    // i.e. the contiguous virtual range [j*512,(j+1)*512): n fast, m slow ->
    // B (1 MB) L2-resident, each A-panel reused 8x within one XCD's L2.
    const int orig = blockIdx.x;
    const int v    = (orig & 7) * 512 + (orig >> 3);
    const int n0   = (v & 7) * 128;
    const int m0   = (v >> 3) * 128;

    v16i acc[2][2];
    #pragma unroll
    for (int a = 0; a < 2; ++a)
        #pragma unroll
        for (int b = 0; b < 2; ++b)
            #pragma unroll
            for (int i = 0; i < 16; ++i) acc[a][b][i] = 0;

    // Staging: per matrix per K-step the tile is 128 rows x 128 B = 1024
    // 16B-chunks; 256 threads take 4 shots. Shot s, thread t covers physical
    // chunk i = s*256+t -> physical row p=i>>3, slot q=i&7. Source chunk is
    // the inverse (== same) swizzle q^(p&7).
    const signed char* gAsrc[4];
    const signed char* gBsrc[4];
    #pragma unroll
    for (int s = 0; s < 4; ++s) {
        int i  = s * 256 + tid;
        int p  = i >> 3;
        int qs = (i & 7) ^ (p & 7);
        gAsrc[s] = A + (size_t)(m0 + p) * 1024 + qs * 16;
        gBsrc[s] = B + (size_t)(n0 + p) * 1024 + qs * 16;
    }
    signed char* lA = As + tid * 16;   // + s*4096 per shot (wave-uniform+lane*16)
    signed char* lB = Bs + tid * 16;

    // Read side: a0 row and a1 row differ by 32 -> same (row&7), same XOR key.
    const int rA = wm * 64 + l31;
    const int rB = wn * 64 + l31;
    const signed char* pA0 = As + rA * 128;
    const signed char* pB0 = Bs + rB * 128;
    const int xA = rA & 7;
    const int xB = rB & 7;

    for (int k0 = 0; k0 < 1024; k0 += 128) {
        #pragma unroll
        for (int s = 0; s < 4; ++s) {
            async_load16(gAsrc[s] + k0, lA + s * 4096);
            async_load16(gBsrc[s] + k0, lB + s * 4096);
        }
        __syncthreads();
        #pragma unroll
        for (int kc = 0; kc < 4; ++kc) {
            const int c  = kc * 2 + lhi;           // logical 16B chunk in row
            const int qa = (c ^ xA) * 16;
            const int qb = (c ^ xB) * 16;
            v4i a0 = *(const v4i*)(pA0 + qa);
            v4i a1 = *(const v4i*)(pA0 + 32 * 128 + qa);
            v4i b0 = *(const v4i*)(pB0 + qb);
            v4i b1 = *(const v4i*)(pB0 + 32 * 128 + qb);
            acc[0][0] = __builtin_amdgcn_mfma_i32_32x32x32_i8(a0, b0, acc[0][0], 0, 0, 0);
            acc[0][1] = __builtin_amdgcn_mfma_i32_32x32x32_i8(a0, b1, acc[0][1], 0, 0, 0);
            acc[1][0] = __builtin_amdgcn_mfma_i32_32x32x32_i8(a1, b0, acc[1][0], 0, 0, 0);
            acc[1][1] = __builtin_amdgcn_mfma_i32_32x32x32_i8(a1, b1, acc[1][1], 0, 0, 0);
        }
        __syncthreads();
    }

    const float inv = scp[0];
    #pragma unroll
    for (int tm = 0; tm < 2; ++tm)
        #pragma unroll
        for (int tn = 0; tn < 2; ++tn)
            #pragma unroll
            for (int r = 0; r < 16; ++r) {
                int row = m0 + wm * 64 + tm * 32 + (r & 3) + 8 * (r >> 2) + 4 * lhi;
                int col = n0 + wn * 64 + tn * 32 + l31;
                out[(size_t)row * 1024 + col] = (float)acc[tm][tn][r] * inv;
            }
}

// ---------------------------------------------------------------------------
extern "C" void kernel_launch(void* const* d_in, const int* in_sizes, int n_in,
                              void* d_out, int out_size, void* d_ws, size_t ws_size,
                              hipStream_t stream) {
    const float* x = (const float*)d_in[0];   // [65536,1024]
    const float* w = (const float*)d_in[1];   // [1024,1024]
    // d_in[2] (bias) is unused by the reference
    float* out = (float*)d_out;               // [65536,1024] fp32

    const int NX = 65536 * 1024;              // x elements
    const int NW = 1024 * 1024;               // w elements

    char* ws = (char*)d_ws;
    unsigned* bits = (unsigned*)ws;           // 2 uints
    float* sc = (float*)(ws + 8);             // 3 floats
    signed char* qx = (signed char*)(ws + 256);
    signed char* qw = qx + (size_t)NX;        // + 64 MB

    k_init<<<1, 64, 0, stream>>>(bits);
    // fused absmax: 2048 x-blocks + 128 w-blocks
    k_absmax2<<<2048 + 128, 256, 0, stream>>>((const float4*)x, NX / 4,
                                              (const float4*)w, NW / 4, bits);
    k_scales<<<1, 1, 0, stream>>>(bits, sc);
    // fused quant: 4096 x-blocks + 128 w-blocks
    k_quant2<<<4096 + 128, 256, 0, stream>>>((const float4*)x, (int*)qx, NX / 4,
                                             (const float4*)w, (int*)qw, NW / 4, sc);

    k_gemm<<<dim3(4096), 256, 0, stream>>>(qx, qw, out, sc + 2);
}